// Round 5
// baseline (349.035 us; speedup 1.0000x reference)
//
#include <hip/hip_runtime.h>

#define NPTS 2048
#define CG   64    // channels per tile (4 tiles per point)
#define NI   83    // true K
#define KP   96    // K padded to 3 * 32
#define PST  104   // patch LDS row stride in bf16
#define OD   256
#define SOR  264   // out-staging row stride (dwords): 16B-aligned, ~4-way conflict

// d_ws layout (ushort elems): wfrag table, then bf16 feature copies
#define FEATB_OFF   24576
#define F2_REL      4194304        // 256*128*128
#define F3_REL      5242880        // + 256*64*64

typedef __attribute__((ext_vector_type(8))) short bf16x8;   // 8 bf16
typedef __attribute__((ext_vector_type(4))) float f32x4;

__device__ __forceinline__ unsigned short f32_to_bf16_rne(float f) {
    union { float f; unsigned int u; } cv; cv.f = f;
    unsigned int u = cv.u;
    u += 0x7fffu + ((u >> 16) & 1u);
    return (unsigned short)(u >> 16);
}

// ---- merged prep: bf16 feature copies + fc_w fragment table ----
__global__ __launch_bounds__(256) void prep_kernel(
    const float* __restrict__ fc_w,
    const float* __restrict__ feat1, const float* __restrict__ feat2,
    const float* __restrict__ feat3, unsigned short* __restrict__ ws)
{
    const int b = blockIdx.x;
    if (b < 2688) {                         // feature convert: 8 elems/thread
        const int s = b * 256 + threadIdx.x;
        unsigned short* featb = ws + FEATB_OFF;
        const float* src;
        size_t e;
        if (s < 524288)      { src = feat1; e = (size_t)s * 8; }
        else if (s < 655360) { src = feat2; e = (size_t)(s - 524288) * 8; featb += F2_REL; }
        else                 { src = feat3; e = (size_t)(s - 655360) * 8; featb += F3_REL; }
        const float4 a = ((const float4*)(src + e))[0];
        const float4 c = ((const float4*)(src + e))[1];
        unsigned short v[8];
        v[0] = f32_to_bf16_rne(a.x); v[1] = f32_to_bf16_rne(a.y);
        v[2] = f32_to_bf16_rne(a.z); v[3] = f32_to_bf16_rne(a.w);
        v[4] = f32_to_bf16_rne(c.x); v[5] = f32_to_bf16_rne(c.y);
        v[6] = f32_to_bf16_rne(c.z); v[7] = f32_to_bf16_rne(c.w);
        *(bf16x8*)(featb + e) = *(const bf16x8*)v;
    } else {                                // W A-fragment table
        const int s = (b - 2688) * 256 + threadIdx.x;   // 0..3071
        const int ot   = s / 192;
        const int rem  = s - ot * 192;
        const int ks   = rem >> 6;
        const int lane = rem & 63;
        const int o    = ot * 16 + (lane & 15);
        const int k0   = ks * 32 + (lane >> 4) * 8;
        unsigned short v[8];
        #pragma unroll
        for (int i = 0; i < 8; ++i) {
            const int k = k0 + i;
            v[i] = (k < NI) ? f32_to_bf16_rne(fc_w[o * NI + k]) : (unsigned short)0;
        }
        ((bf16x8*)ws)[s] = *(const bf16x8*)v;
    }
}

// ---- main: per-point block, 4 channel-group tiles, double-buffered gather ----
__global__ __launch_bounds__(256) void sampler_fc_kernel(
    const float* __restrict__ points,
    const unsigned short* __restrict__ featb,
    const unsigned short* __restrict__ wfrag,
    const float* __restrict__ fc_b,
    float* __restrict__ out)
{
    __shared__ int sAddr[KP];
    __shared__ int sStep[KP];
    __shared__ __align__(16) unsigned short P[2][CG * PST];  // double-buffered patches
    __shared__ __align__(16) float Sout[16 * SOR];           // epilogue staging

    const int n   = blockIdx.x;
    const int tid = threadIdx.x;
    const int wv  = tid >> 6;
    const int l   = tid & 63;

    // spatial index tables — once per point
    if (tid < KP) {
        int addr = 0, step = 0;
        if (tid < NI) {
            const float px = points[n * 2 + 0];
            const float py = points[n * 2 + 1];
            int i = tid;
            int k, Wl, j, baseRel;
            if (i < 49)      { k = 7; Wl = 128; j = i;      baseRel = 0; }
            else if (i < 74) { k = 5; Wl = 64;  j = i - 49; baseRel = F2_REL; }
            else             { k = 3; Wl = 32;  j = i - 74; baseRel = F3_REL; }
            const int   half = k >> 1;
            const float wm1  = (float)(Wl - 1);
            const float x = fminf(fmaxf(px * wm1, 0.f), wm1);
            const float y = fminf(fmaxf(py * wm1, 0.f), wm1);
            const float dx = (float)(j % k - half);
            const float dy = (float)(j / k - half);
            const int ox = (int)fminf(fmaxf(x + dx, 0.f), wm1);
            const int oy = (int)fminf(fmaxf(y + dy, 0.f), wm1);
            addr = baseRel + oy * Wl + ox;
            step = Wl * Wl;
        }
        sAddr[tid] = addr;
        sStep[tid] = step;
    }

    // W fragments + bias — once per point (constant across the 4 tiles)
    bf16x8 wfr[4][3];
    #pragma unroll
    for (int ot = 0; ot < 4; ++ot)
        #pragma unroll
        for (int ks = 0; ks < 3; ++ks)
            wfr[ot][ks] = ((const bf16x8*)wfrag)[((wv * 4 + ot) * 3 + ks) * 64 + l];

    f32x4 b4[4];
    #pragma unroll
    for (int ot = 0; ot < 4; ++ot)
        b4[ot] = *(const f32x4*)&fc_b[wv * 64 + ot * 16 + ((l >> 4) << 2)];

    __syncthreads();   // tables ready

    // prologue: gather tile 0
    #pragma unroll
    for (int it = 0; it < 24; ++it) {
        const int t  = tid + it * 256;
        const int cl = t / KP;
        const int i  = t - cl * KP;
        unsigned short v = 0;
        const int step = sStep[i];
        if (step) v = featb[(size_t)(sAddr[i] + cl * step)];
        P[0][cl * PST + i] = v;
    }

    int cur = 0;
    for (int cg = 0; cg < 4; ++cg) {
        __syncthreads();   // P[cur] visible; Sout free

        // issue next tile's gather early — hides under MFMA + epilogue
        if (cg < 3) {
            #pragma unroll
            for (int it = 0; it < 24; ++it) {
                const int t  = tid + it * 256;
                const int cl = t / KP;
                const int i  = t - cl * KP;
                unsigned short v = 0;
                const int step = sStep[i];
                if (step) v = featb[(size_t)(sAddr[i] + ((cg + 1) * CG + cl) * step)];
                P[cur ^ 1][cl * PST + i] = v;
            }
        }

        // MFMA on current tile
        f32x4 acc[4][4];
        #pragma unroll
        for (int ot = 0; ot < 4; ++ot)
            #pragma unroll
            for (int ct = 0; ct < 4; ++ct)
                acc[ot][ct] = (f32x4)(0.f);

        #pragma unroll
        for (int ks = 0; ks < 3; ++ks) {
            bf16x8 pfr[4];
            #pragma unroll
            for (int ct = 0; ct < 4; ++ct) {
                const int ch  = ct * 16 + (l & 15);
                const int kof = ks * 32 + ((l >> 4) << 3);
                pfr[ct] = *(const bf16x8*)&P[cur][ch * PST + kof];
            }
            #pragma unroll
            for (int ot = 0; ot < 4; ++ot)
                #pragma unroll
                for (int ct = 0; ct < 4; ++ct)
                    acc[ot][ct] = __builtin_amdgcn_mfma_f32_16x16x32_bf16(
                        wfr[ot][ks], pfr[ct], acc[ot][ct], 0, 0, 0);
        }

        // epilogue: LDS transpose -> 1KB contiguous NT bursts
        #pragma unroll
        for (int ct = 0; ct < 4; ++ct) {
            #pragma unroll
            for (int ot = 0; ot < 4; ++ot) {
                f32x4 v;
                #pragma unroll
                for (int j = 0; j < 4; ++j) v[j] = acc[ot][ct][j] + b4[ot][j];
                const int ch = l & 15;
                const int o  = wv * 64 + ot * 16 + ((l >> 4) << 2);
                *(f32x4*)&Sout[ch * SOR + o] = v;
            }
            __syncthreads();
            #pragma unroll
            for (int r = 0; r < 4; ++r) {
                const int ch = wv * 4 + r;
                const int c  = cg * CG + ct * 16 + ch;
                const f32x4 v = *(const f32x4*)&Sout[ch * SOR + l * 4];
                __builtin_nontemporal_store(v, (f32x4*)(out + ((size_t)c * NPTS + n) * OD + l * 4));
            }
            __syncthreads();
        }

        cur ^= 1;
    }
}

extern "C" void kernel_launch(void* const* d_in, const int* in_sizes, int n_in,
                              void* d_out, int out_size, void* d_ws, size_t ws_size,
                              hipStream_t stream) {
    (void)in_sizes; (void)n_in; (void)out_size; (void)ws_size;
    const float* points = (const float*)d_in[0];
    const float* feat1  = (const float*)d_in[1];
    const float* feat2  = (const float*)d_in[2];
    const float* feat3  = (const float*)d_in[3];
    const float* fc_w   = (const float*)d_in[4];
    const float* fc_b   = (const float*)d_in[5];
    float* out = (float*)d_out;

    unsigned short* ws    = (unsigned short*)d_ws;
    unsigned short* featb = ws + FEATB_OFF;

    prep_kernel<<<2700, 256, 0, stream>>>(fc_w, feat1, feat2, feat3, ws);
    sampler_fc_kernel<<<NPTS, 256, 0, stream>>>(points, featb, ws, fc_b, out);
}

// Round 7
// 115.814 us; speedup vs baseline: 3.0138x; 3.0138x over previous
//
#include <hip/hip_runtime.h>

#define NPTS 2048
#define NI   83    // true K (samples)
#define KP   96    // K padded to 3*32
#define PST  104   // P row stride in ushorts (c-major, k contiguous) — r4-proven
#define OD   256
#define SOR  260   // out-staging row stride (dwords): 2-way conflict (free)

// d_ws layout (ushort elems): wfrag table (3072*8), then bf16 HWC features
#define FEATB_OFF 24576
#define F2_REL    4194304   // 16384 pix * 256 c
#define F3_REL    5242880   // + 4096 * 256

typedef __attribute__((ext_vector_type(8))) short bf16x8;   // 8 bf16 (4 VGPRs)
typedef __attribute__((ext_vector_type(4))) float f32x4;
typedef __attribute__((ext_vector_type(4))) unsigned short ushort4v;

__device__ __forceinline__ unsigned short f32_to_bf16_rne(float f) {
    union { float f; unsigned int u; } cv; cv.f = f;
    unsigned int u = cv.u;
    u += 0x7fffu + ((u >> 16) & 1u);
    return (unsigned short)(u >> 16);
}

// ---- prep: blocks 0..335 transpose CHW fp32 -> HWC bf16; 336..347 W table ----
__global__ __launch_bounds__(256) void prep_kernel(
    const float* __restrict__ fc_w,
    const float* __restrict__ feat1, const float* __restrict__ feat2,
    const float* __restrict__ feat3, unsigned short* __restrict__ ws)
{
    const int b = blockIdx.x, t = threadIdx.x;
    if (b < 336) {
        const float* src; int HW, pixL0; size_t dstBase;
        if (b < 256)      { src = feat1; HW = 16384; pixL0 = b * 64;         dstBase = 0; }
        else if (b < 320) { src = feat2; HW = 4096;  pixL0 = (b - 256) * 64; dstBase = F2_REL; }
        else              { src = feat3; HW = 1024;  pixL0 = (b - 320) * 64; dstBase = F3_REL; }
        unsigned short* featb = ws + FEATB_OFF + dstBase;
        const int c0 = (t & 63) * 4;              // 4 channels per thread
        const int p0 = pixL0 + (t >> 6) * 16;     // 16 pixels per thread
        #pragma unroll
        for (int jq = 0; jq < 4; ++jq) {
            f32x4 f[4];
            #pragma unroll
            for (int m = 0; m < 4; ++m)
                f[m] = *(const f32x4*)&src[(size_t)(c0 + m) * HW + p0 + jq * 4];
            #pragma unroll
            for (int j = 0; j < 4; ++j) {
                ushort4v v;
                v[0] = f32_to_bf16_rne(f[0][j]);
                v[1] = f32_to_bf16_rne(f[1][j]);
                v[2] = f32_to_bf16_rne(f[2][j]);
                v[3] = f32_to_bf16_rne(f[3][j]);
                *(ushort4v*)(featb + (size_t)(p0 + jq * 4 + j) * 256 + c0) = v;
            }
        }
    } else {
        // W A-fragment table: slot s = ot*192 + ks*64 + lane
        // lane's 8 vals: o = ot*16 + (l&15), k = ks*32 + (l>>4)*8 + i
        const int s = (b - 336) * 256 + t;        // 0..3071
        const int ot   = s / 192;
        const int rem  = s - ot * 192;
        const int ks   = rem >> 6;
        const int lane = rem & 63;
        const int o    = ot * 16 + (lane & 15);
        const int k0   = ks * 32 + (lane >> 4) * 8;
        unsigned short v[8];
        #pragma unroll
        for (int i = 0; i < 8; ++i) {
            const int k = k0 + i;
            v[i] = (k < NI) ? f32_to_bf16_rne(fc_w[o * NI + k]) : (unsigned short)0;
        }
        ((bf16x8*)ws)[s] = *(const bf16x8*)v;
    }
}

// ---- main: transposing coalesced gather -> P[c][k] LDS -> MFMA -> 1KB NT stores ----
__global__ __launch_bounds__(256) void sampler_fc_kernel(
    const float* __restrict__ points,
    const unsigned short* __restrict__ featb,
    const unsigned short* __restrict__ wfrag,
    const float* __restrict__ fc_b,
    float* __restrict__ out)
{
    __shared__ int sAddr[KP];
    // P (64*104*2 = 13312B) and Sout (16*260*4 = 16640B) are time-disjoint
    __shared__ __align__(16) unsigned char smem[16 * SOR * 4];
    unsigned short* P    = (unsigned short*)smem;
    float*          Sout = (float*)smem;

    const int bid = blockIdx.x;
    const int n   = bid >> 2;
    const int cg  = bid & 3;
    const int tid = threadIdx.x;
    const int wv  = tid >> 6;
    const int l   = tid & 63;

    // phase 1: per-point sample base addresses in featb (incl. cg slice), -1 = pad
    if (tid < KP) {
        int addr = -1;
        if (tid < NI) {
            const float px = points[n * 2 + 0];
            const float py = points[n * 2 + 1];
            int i = tid;
            int k, Wl, j, pixBase;
            if (i < 49)      { k = 7; Wl = 128; j = i;      pixBase = 0; }
            else if (i < 74) { k = 5; Wl = 64;  j = i - 49; pixBase = 16384; }
            else             { k = 3; Wl = 32;  j = i - 74; pixBase = 20480; }
            const int   half = k >> 1;
            const float wm1  = (float)(Wl - 1);
            const float x = fminf(fmaxf(px * wm1, 0.f), wm1);
            const float y = fminf(fmaxf(py * wm1, 0.f), wm1);
            const float dx = (float)(j % k - half);
            const float dy = (float)(j / k - half);
            const int ox = (int)fminf(fmaxf(x + dx, 0.f), wm1);
            const int oy = (int)fminf(fmaxf(y + dy, 0.f), wm1);
            addr = (pixBase + oy * Wl + ox) * 256 + cg * 64;
        }
        sAddr[tid] = addr;
    }

    // W fragments (A operand) + bias
    bf16x8 wfr[4][3];
    #pragma unroll
    for (int ot = 0; ot < 4; ++ot)
        #pragma unroll
        for (int ks = 0; ks < 3; ++ks)
            wfr[ot][ks] = ((const bf16x8*)wfrag)[((wv * 4 + ot) * 3 + ks) * 64 + l];

    f32x4 b4[4];
    #pragma unroll
    for (int ot = 0; ot < 4; ++ot)
        b4[ot] = *(const f32x4*)&fc_b[wv * 64 + ot * 16 + ((l >> 4) << 2)];

    __syncthreads();

    // phase 2: transposing gather. thread = (channel c = l, k-octet koct).
    // Each global load instruction: whole wave reads 64 consecutive channels of
    // ONE sample (128B contiguous). After 8 loads the thread holds 8 consecutive
    // k for fixed c == the B-fragment lane data. One ds_write_b128 into P[c][k].
    #pragma unroll
    for (int it = 0; it < 3; ++it) {
        const int c    = l;
        const int koct = wv + it * 4;        // wave-uniform
        unsigned short v[8];
        #pragma unroll
        for (int j = 0; j < 8; ++j) {
            const int a = sAddr[koct * 8 + j];   // wave-uniform broadcast read
            v[j] = (a >= 0) ? featb[(size_t)a + c] : (unsigned short)0;
        }
        *(bf16x8*)&P[c * PST + koct * 8] = *(const bf16x8*)v;
    }
    __syncthreads();

    // phase 3: MFMA. B fragment (patches): ch = ct*16 + (l&15), k = ks*32 + (l>>4)*8
    f32x4 acc[4][4];
    #pragma unroll
    for (int ot = 0; ot < 4; ++ot)
        #pragma unroll
        for (int ct = 0; ct < 4; ++ct)
            acc[ot][ct] = (f32x4)(0.f);

    #pragma unroll
    for (int ks = 0; ks < 3; ++ks) {
        bf16x8 pfr[4];
        #pragma unroll
        for (int ct = 0; ct < 4; ++ct) {
            const int ch  = ct * 16 + (l & 15);
            const int kof = ks * 32 + ((l >> 4) << 3);
            pfr[ct] = *(const bf16x8*)&P[ch * PST + kof];
        }
        #pragma unroll
        for (int ot = 0; ot < 4; ++ot)
            #pragma unroll
            for (int ct = 0; ct < 4; ++ct)
                acc[ot][ct] = __builtin_amdgcn_mfma_f32_16x16x32_bf16(
                    wfr[ot][ks], pfr[ct], acc[ot][ct], 0, 0, 0);
    }

    __syncthreads();   // P dead; smem reused as Sout

    // phase 4: epilogue via LDS transpose -> 1KB contiguous NT bursts
    #pragma unroll
    for (int ct = 0; ct < 4; ++ct) {
        #pragma unroll
        for (int ot = 0; ot < 4; ++ot) {
            f32x4 v;
            #pragma unroll
            for (int j = 0; j < 4; ++j) v[j] = acc[ot][ct][j] + b4[ot][j];
            const int ch = l & 15;
            const int o  = wv * 64 + ot * 16 + ((l >> 4) << 2);
            *(f32x4*)&Sout[ch * SOR + o] = v;
        }
        __syncthreads();
        #pragma unroll
        for (int r = 0; r < 4; ++r) {
            const int ch = wv * 4 + r;
            const int c  = cg * 64 + ct * 16 + ch;
            const f32x4 v = *(const f32x4*)&Sout[ch * SOR + l * 4];
            __builtin_nontemporal_store(v, (f32x4*)(out + ((size_t)c * NPTS + n) * OD + l * 4));
        }
        __syncthreads();
    }
}

extern "C" void kernel_launch(void* const* d_in, const int* in_sizes, int n_in,
                              void* d_out, int out_size, void* d_ws, size_t ws_size,
                              hipStream_t stream) {
    (void)in_sizes; (void)n_in; (void)out_size; (void)ws_size;
    const float* points = (const float*)d_in[0];
    const float* feat1  = (const float*)d_in[1];
    const float* feat2  = (const float*)d_in[2];
    const float* feat3  = (const float*)d_in[3];
    const float* fc_w   = (const float*)d_in[4];
    const float* fc_b   = (const float*)d_in[5];
    float* out = (float*)d_out;

    unsigned short* ws    = (unsigned short*)d_ws;
    unsigned short* featb = ws + FEATB_OFF;

    prep_kernel<<<348, 256, 0, stream>>>(fc_w, feat1, feat2, feat3, ws);
    sampler_fc_kernel<<<NPTS * 4, 256, 0, stream>>>(points, featb, ws, fc_b, out);
}

// Round 8
// 108.153 us; speedup vs baseline: 3.2272x; 1.0708x over previous
//
#include <hip/hip_runtime.h>

#define NPTS 2048
#define NI   83    // true K (samples)
#define KP   96    // K padded to 3*32
#define PST  104   // P row stride in ushorts (c-major, k contiguous)
#define OD   256
#define SOR  260   // out-staging row stride (dwords): 2-way conflict (free)

// d_ws layout (ushort elems): wfrag table (3072*8), then bf16 HWC features
#define FEATB_OFF 24576
#define F2_REL    4194304   // 16384 pix * 256 c
#define F3_REL    5242880   // + 4096 * 256

typedef __attribute__((ext_vector_type(8))) short bf16x8;   // 8 bf16 (4 VGPRs)
typedef __attribute__((ext_vector_type(4))) float f32x4;
typedef __attribute__((ext_vector_type(4))) unsigned short ushort4v;

__device__ __forceinline__ unsigned short f32_to_bf16_rne(float f) {
    union { float f; unsigned int u; } cv; cv.f = f;
    unsigned int u = cv.u;
    u += 0x7fffu + ((u >> 16) & 1u);
    return (unsigned short)(u >> 16);
}

// ---- prep: blocks 0..335 transpose CHW fp32 -> HWC bf16; 336..347 W table ----
__global__ __launch_bounds__(256) void prep_kernel(
    const float* __restrict__ fc_w,
    const float* __restrict__ feat1, const float* __restrict__ feat2,
    const float* __restrict__ feat3, unsigned short* __restrict__ ws)
{
    const int b = blockIdx.x, t = threadIdx.x;
    if (b < 336) {
        const float* src; int HW, pixL0; size_t dstBase;
        if (b < 256)      { src = feat1; HW = 16384; pixL0 = b * 64;         dstBase = 0; }
        else if (b < 320) { src = feat2; HW = 4096;  pixL0 = (b - 256) * 64; dstBase = F2_REL; }
        else              { src = feat3; HW = 1024;  pixL0 = (b - 320) * 64; dstBase = F3_REL; }
        unsigned short* featb = ws + FEATB_OFF + dstBase;
        const int c0 = (t & 63) * 4;              // 4 channels per thread
        const int p0 = pixL0 + (t >> 6) * 16;     // 16 pixels per thread
        #pragma unroll
        for (int jq = 0; jq < 4; ++jq) {
            f32x4 f[4];
            #pragma unroll
            for (int m = 0; m < 4; ++m)
                f[m] = *(const f32x4*)&src[(size_t)(c0 + m) * HW + p0 + jq * 4];
            #pragma unroll
            for (int j = 0; j < 4; ++j) {
                ushort4v v;
                v[0] = f32_to_bf16_rne(f[0][j]);
                v[1] = f32_to_bf16_rne(f[1][j]);
                v[2] = f32_to_bf16_rne(f[2][j]);
                v[3] = f32_to_bf16_rne(f[3][j]);
                *(ushort4v*)(featb + (size_t)(p0 + jq * 4 + j) * 256 + c0) = v;
            }
        }
    } else {
        // W A-fragment table: slot s = ot*192 + ks*64 + lane
        // lane's 8 vals: o = ot*16 + (l&15), k = ks*32 + (l>>4)*8 + i
        const int s = (b - 336) * 256 + t;        // 0..3071
        const int ot   = s / 192;
        const int rem  = s - ot * 192;
        const int ks   = rem >> 6;
        const int lane = rem & 63;
        const int o    = ot * 16 + (lane & 15);
        const int k0   = ks * 32 + (lane >> 4) * 8;
        unsigned short v[8];
        #pragma unroll
        for (int i = 0; i < 8; ++i) {
            const int k = k0 + i;
            v[i] = (k < NI) ? f32_to_bf16_rne(fc_w[o * NI + k]) : (unsigned short)0;
        }
        ((bf16x8*)ws)[s] = *(const bf16x8*)v;
    }
}

// ---- main: transposing coalesced gather -> P[c][k] LDS -> per-ct MFMA+store ----
__global__ __launch_bounds__(256, 4) void sampler_fc_kernel(
    const float* __restrict__ points,
    const unsigned short* __restrict__ featb,
    const unsigned short* __restrict__ wfrag,
    const float* __restrict__ fc_b,
    float* __restrict__ out)
{
    __shared__ int sAddr[KP];
    __shared__ __align__(16) unsigned short P[64 * PST];   // 13312 B, live all cts
    __shared__ __align__(16) float Sout[16 * SOR];          // 16640 B per-ct staging

    const int bid = blockIdx.x;
    const int n   = bid >> 2;
    const int cg  = bid & 3;
    const int tid = threadIdx.x;
    const int wv  = tid >> 6;
    const int l   = tid & 63;

    // phase 1: per-point sample base addresses in featb (incl. cg slice), -1 = pad
    if (tid < KP) {
        int addr = -1;
        if (tid < NI) {
            const float px = points[n * 2 + 0];
            const float py = points[n * 2 + 1];
            int i = tid;
            int k, Wl, j, pixBase;
            if (i < 49)      { k = 7; Wl = 128; j = i;      pixBase = 0; }
            else if (i < 74) { k = 5; Wl = 64;  j = i - 49; pixBase = 16384; }
            else             { k = 3; Wl = 32;  j = i - 74; pixBase = 20480; }
            const int   half = k >> 1;
            const float wm1  = (float)(Wl - 1);
            const float x = fminf(fmaxf(px * wm1, 0.f), wm1);
            const float y = fminf(fmaxf(py * wm1, 0.f), wm1);
            const float dx = (float)(j % k - half);
            const float dy = (float)(j / k - half);
            const int ox = (int)fminf(fmaxf(x + dx, 0.f), wm1);
            const int oy = (int)fminf(fmaxf(y + dy, 0.f), wm1);
            addr = (pixBase + oy * Wl + ox) * 256 + cg * 64;
        }
        sAddr[tid] = addr;
    }

    // W fragments (A operand) + bias — wfr 48 VGPRs, b4 16
    bf16x8 wfr[4][3];
    #pragma unroll
    for (int ot = 0; ot < 4; ++ot)
        #pragma unroll
        for (int ks = 0; ks < 3; ++ks)
            wfr[ot][ks] = ((const bf16x8*)wfrag)[((wv * 4 + ot) * 3 + ks) * 64 + l];

    f32x4 b4[4];
    #pragma unroll
    for (int ot = 0; ot < 4; ++ot)
        b4[ot] = *(const f32x4*)&fc_b[wv * 64 + ot * 16 + ((l >> 4) << 2)];

    __syncthreads();

    // phase 2: transposing gather — wave reads 64 consecutive channels of ONE
    // sample per instruction (128B coalesced); thread accumulates 8 k for its c.
    #pragma unroll
    for (int it = 0; it < 3; ++it) {
        const int c    = l;
        const int koct = wv + it * 4;        // wave-uniform
        unsigned short v[8];
        #pragma unroll
        for (int j = 0; j < 8; ++j) {
            const int a = sAddr[koct * 8 + j];
            v[j] = (a >= 0) ? featb[(size_t)a + c] : (unsigned short)0;
        }
        *(bf16x8*)&P[c * PST + koct * 8] = *(const bf16x8*)v;
    }
    __syncthreads();

    // phase 3: per-ct: 3 pfr reads, 12 MFMAs (acc only 16 VGPRs live), stage, store
    #pragma unroll
    for (int ct = 0; ct < 4; ++ct) {
        f32x4 acc[4];
        #pragma unroll
        for (int ot = 0; ot < 4; ++ot) acc[ot] = (f32x4)(0.f);

        #pragma unroll
        for (int ks = 0; ks < 3; ++ks) {
            const int ch  = ct * 16 + (l & 15);
            const int kof = ks * 32 + ((l >> 4) << 3);
            const bf16x8 pfr = *(const bf16x8*)&P[ch * PST + kof];
            #pragma unroll
            for (int ot = 0; ot < 4; ++ot)
                acc[ot] = __builtin_amdgcn_mfma_f32_16x16x32_bf16(
                    wfr[ot][ks], pfr, acc[ot], 0, 0, 0);
        }

        // stage: D layout col = l&15 = channel(within ct), row = o (consecutive 4)
        #pragma unroll
        for (int ot = 0; ot < 4; ++ot) {
            f32x4 v;
            #pragma unroll
            for (int j = 0; j < 4; ++j) v[j] = acc[ot][j] + b4[ot][j];
            const int ch = l & 15;
            const int o  = wv * 64 + ot * 16 + ((l >> 4) << 2);
            *(f32x4*)&Sout[ch * SOR + o] = v;
        }
        __syncthreads();
        // each wave streams 4 whole (c,n,:) rows — 1KB contiguous NT bursts
        #pragma unroll
        for (int r = 0; r < 4; ++r) {
            const int ch = wv * 4 + r;
            const int c  = cg * 64 + ct * 16 + ch;
            const f32x4 v = *(const f32x4*)&Sout[ch * SOR + l * 4];
            __builtin_nontemporal_store(v, (f32x4*)(out + ((size_t)c * NPTS + n) * OD + l * 4));
        }
        __syncthreads();   // Sout reuse guard for next ct
    }
}

extern "C" void kernel_launch(void* const* d_in, const int* in_sizes, int n_in,
                              void* d_out, int out_size, void* d_ws, size_t ws_size,
                              hipStream_t stream) {
    (void)in_sizes; (void)n_in; (void)out_size; (void)ws_size;
    const float* points = (const float*)d_in[0];
    const float* feat1  = (const float*)d_in[1];
    const float* feat2  = (const float*)d_in[2];
    const float* feat3  = (const float*)d_in[3];
    const float* fc_w   = (const float*)d_in[4];
    const float* fc_b   = (const float*)d_in[5];
    float* out = (float*)d_out;

    unsigned short* ws    = (unsigned short*)d_ws;
    unsigned short* featb = ws + FEATB_OFF;

    prep_kernel<<<348, 256, 0, stream>>>(fc_w, feat1, feat2, feat3, ws);
    sampler_fc_kernel<<<NPTS * 4, 256, 0, stream>>>(points, featb, ws, fc_b, out);
}